// Round 11
// baseline (58.868 us; speedup 1.0000x reference)
//
#include <hip/hip_runtime.h>

// R11 = byte-exact revert to the R6 kernel (last passing, 58.87 us).
// R7-R10 all failed with identical absmax 4.625 under four different
// perturbations of conv_kernel and/or its co-compiled siblings (setprio,
// asm-barrier variant, loop rotation w/ sched_barrier, convert rewrite).
// Conclusion: this conv schedule is perturbation-fragile; do not modify
// conv_kernel or co-compiled kernels without a full re-validation plan.

#define BB 16
#define CC 128
#define HH 64
#define WW 64
#define OO 128
#define KK 4
#define RR 32
#define KTOT 1152          // 9 * 128
#define NT 36              // K-steps of 32
#define XP 66              // padded spatial dim

typedef short v8s __attribute__((ext_vector_type(8)));
typedef float v4f __attribute__((ext_vector_type(4)));

__device__ __forceinline__ unsigned short f2bf(float f) {
    unsigned u = __builtin_bit_cast(unsigned, f);
    u += 0x7fffu + ((u >> 16) & 1u);
    return (unsigned short)(u >> 16);
}

// async global->LDS, 16B per lane; LDS dest is wave-uniform base + lane*16
__device__ __forceinline__ void gl16(const unsigned short* g, unsigned short* l) {
    __builtin_amdgcn_global_load_lds(
        (const __attribute__((address_space(1))) unsigned int*)g,
        (__attribute__((address_space(3))) unsigned int*)l, 16, 0, 0);
}

// ---------------- kernel 1: convert fp32 NCHW -> bf16 padded NHWC + halo zero + pool partials ----
// grid 4096 = (b:4bits)(g:4bits)(pxblk:4bits), 256 thr. No atomics: per-block partial sums.
__global__ __launch_bounds__(256) void convert_pool_kernel(const float* __restrict__ x,
        unsigned short* __restrict__ xbp, float* __restrict__ part) {
    int bid = blockIdx.x;
    int t = threadIdx.x;
    int p = (bid & 15) * 256 + t;
    int g = (bid >> 4) & 15;
    int b = bid >> 8;
    const float* xp = x + ((size_t)(b * CC + g * 8)) * 4096 + p;
    float vals[8];
    v8s v;
    #pragma unroll
    for (int j = 0; j < 8; ++j) {
        vals[j] = xp[(size_t)j * 4096];
        v[j] = (short)f2bf(vals[j]);
    }
    int h = p >> 6, w = p & 63;
    unsigned short* xb_b = xbp + (size_t)b * XP * XP * CC + g * 8;
    *(v8s*)(xb_b + (size_t)((h + 1) * XP + w + 1) * CC) = v;

    // halo zeros (edge threads only)
    v8s z = (v8s)0;
    if (w == 0)  *(v8s*)(xb_b + (size_t)((h + 1) * XP) * CC) = z;
    if (w == 63) *(v8s*)(xb_b + (size_t)((h + 1) * XP + 65) * CC) = z;
    if (h == 0)  *(v8s*)(xb_b + (size_t)(w + 1) * CC) = z;
    if (h == 63) *(v8s*)(xb_b + (size_t)(65 * XP + w + 1) * CC) = z;
    if (h == 0 && w == 0)   *(v8s*)(xb_b + 0) = z;
    if (h == 0 && w == 63)  *(v8s*)(xb_b + (size_t)65 * CC) = z;
    if (h == 63 && w == 0)  *(v8s*)(xb_b + (size_t)(65 * XP) * CC) = z;
    if (h == 63 && w == 63) *(v8s*)(xb_b + (size_t)(65 * XP + 65) * CC) = z;

    // pool partials: sum over this block's 256 px for 8 channels
    __shared__ float ls[4][8];
    int lane = t & 63, wv = t >> 6;
    #pragma unroll
    for (int j = 0; j < 8; ++j) {
        float s = vals[j];
        #pragma unroll
        for (int off = 32; off > 0; off >>= 1) s += __shfl_down(s, off, 64);
        if (lane == 0) ls[wv][j] = s;
    }
    __syncthreads();
    if (t < 8) {
        float s = ls[0][t] + ls[1][t] + ls[2][t] + ls[3][t];
        // part[b][g][pxblk][j]
        part[(((b * 16 + g) * 16) + (bid & 15)) * 8 + t] = s;
    }
}

// ---------------- kernel 2: pool-reduce + SE-MLP + softmax + bank mix -> bf16 A [b][o][tap*128+c] ----
__global__ __launch_bounds__(256) void mix_kernel(const float* __restrict__ kernels,
        const float* __restrict__ part,
        const float* __restrict__ w1, const float* __restrict__ b1,
        const float* __restrict__ w2, const float* __restrict__ b2,
        unsigned short* __restrict__ wmixb) {
    const int b = blockIdx.y, o = blockIdx.x;
    const int t = threadIdx.x;
    __shared__ float pooled_sh[CC];
    __shared__ float hs[RR];
    __shared__ float lgs[KK];
    __shared__ float attns[KK];
    __shared__ unsigned short ws[KTOT];

    if (t < CC) {
        const float* pp = part + ((b * 16 + (t >> 3)) * 16) * 8 + (t & 7);
        float s = 0.f;
        #pragma unroll
        for (int pb = 0; pb < 16; ++pb) s += pp[pb * 8];
        pooled_sh[t] = s * (1.0f / 4096.0f);
    }
    __syncthreads();
    if (t < RR) {
        float acc = b1[t];
        const float* wr = w1 + t * CC;
        for (int c = 0; c < CC; ++c) acc += pooled_sh[c] * wr[c];
        hs[t] = fmaxf(acc, 0.f);
    }
    __syncthreads();
    if (t < KK) {
        float a = b2[t];
        #pragma unroll
        for (int r = 0; r < RR; ++r) a += hs[r] * w2[t * RR + r];
        lgs[t] = a;
    }
    __syncthreads();
    if (t == 0) {
        float m = fmaxf(fmaxf(lgs[0], lgs[1]), fmaxf(lgs[2], lgs[3]));
        float e0 = expf(lgs[0] - m), e1 = expf(lgs[1] - m);
        float e2 = expf(lgs[2] - m), e3 = expf(lgs[3] - m);
        float inv = 1.f / (e0 + e1 + e2 + e3);
        attns[0] = e0 * inv; attns[1] = e1 * inv; attns[2] = e2 * inv; attns[3] = e3 * inv;
    }
    __syncthreads();
    float a0 = attns[0], a1 = attns[1], a2 = attns[2], a3 = attns[3];

    const size_t KB = (size_t)OO * KTOT;
    const float* k0 = kernels + (size_t)o * KTOT;
    for (int ii = t; ii < KTOT; ii += 256) {
        int c = ii / 9, tap = ii - c * 9;
        float v = a0 * k0[ii] + a1 * k0[KB + ii] + a2 * k0[2 * KB + ii] + a3 * k0[3 * KB + ii];
        ws[tap * 128 + c] = f2bf(v);
    }
    __syncthreads();
    v8s* wp8 = (v8s*)(wmixb + ((size_t)b * OO + o) * KTOT);
    const v8s* ls8 = (const v8s*)ws;
    for (int ii = t; ii < KTOT / 8; ii += 256) wp8[ii] = ls8[ii];
}

// ---------------- kernel 3: implicit-GEMM conv, 3-deep counted-vmcnt pipeline ----------------
// grid 512 = 8 XCD * (2 b * 32 ntiles). 256 thr = 4 waves (wm = o-half, wn = row-of-2).
// Per K-step (32 k): A-tile [128 o][32 k] + B-tile [128 p][32 c] staged via global_load_lds.
// Counted vmcnt: tile k+1's loads stay in flight across the barrier (T3/T4).
// DO NOT PERTURB: R7-R10 showed any scheduling change here (s_setprio, asm-barrier
// variants, loop rotation) flips this kernel into deterministic corruption (absmax 4.625).
#define MFMA16(acc, va, vb) \
    asm volatile("v_mfma_f32_16x16x32_bf16 %0, %1, %2, %0" : "+v"(acc) : "v"(va), "v"(vb))

#define STAGE(ks_, buf_) { \
    const int tap_ = (ks_) >> 2; \
    const int dy_ = tap_ / 3, dx_ = tap_ % 3; \
    const int c0_ = ((ks_) & 3) * 32; \
    const unsigned short* sa_ = srcA0 + (ks_) * 32; \
    const unsigned short* sb_ = srcB0 + ((size_t)(dy_ * XP + dx_)) * CC + c0_; \
    gl16(sa_,                     &Ab[buf_][wid * 512]); \
    gl16(sa_ + (size_t)64 * KTOT, &Ab[buf_][(wid + 4) * 512]); \
    gl16(sb_,                     &Bb[buf_][wid * 512]); \
    gl16(sb_ + XP * CC,           &Bb[buf_][(wid + 4) * 512]); \
}

__global__ __launch_bounds__(256, 2) void conv_kernel(
        const unsigned short* __restrict__ xbp,
        const unsigned short* __restrict__ wmixb,
        float* __restrict__ out) {
    __shared__ unsigned short Ab[3][4096];   // [128 o][32 k] bf16, 8KB each
    __shared__ unsigned short Bb[3][4096];   // [128 p][32 c]
    int bid = blockIdx.x;
    int xcd = bid & 7, idx = bid >> 3;
    int b = xcd * 2 + (idx >> 5);
    int nt = idx & 31;
    int t = threadIdx.x;
    int lane = t & 63, wid = t >> 6;
    int wm = wid & 1, wn = wid >> 1;   // wn in {0,1}

    v4f acc[4][4];
    #pragma unroll
    for (int i = 0; i < 4; ++i)
        #pragma unroll
        for (int j = 0; j < 4; ++j) acc[i][j] = (v4f)0.f;

    // staging source bases (per thread): chunk rows = wid*16 + (lane>>2), chunk g = lane&3
    int l4 = lane >> 2, g = lane & 3;
    const unsigned short* srcA0 = wmixb + ((size_t)(b * OO + wid * 16 + l4)) * KTOT + g * 8;
    const unsigned short* srcB0 = xbp + ((size_t)((b * XP + nt * 2) * XP) + wid * 16 + l4) * CC + g * 8;
    // fragment read base (bytes into tile): row = lane&15 (+16*mf), chunk = lane>>4
    int lane_off = (lane & 15) * 64 + (lane >> 4) * 16;

    STAGE(0, 0);
    STAGE(1, 1);

    #pragma unroll
    for (int ks = 0; ks < NT; ++ks) {
        if (ks == NT - 1) {
            asm volatile("s_waitcnt vmcnt(0)" ::: "memory");
        } else {
            asm volatile("s_waitcnt vmcnt(4)" ::: "memory");
        }
        __builtin_amdgcn_s_barrier();
        if (ks + 2 < NT) STAGE(ks + 2, (ks + 2) % 3);
        const int buf_ = ks % 3;
        v8s af[4], bfv[4];
        const char* abase = (const char*)&Ab[buf_][0] + wm * 4096 + lane_off;
        const char* bbase = (const char*)&Bb[buf_][0] + wn * 4096 + lane_off;
        #pragma unroll
        for (int mf = 0; mf < 4; ++mf) af[mf] = *(const v8s*)(abase + mf * 1024);
        #pragma unroll
        for (int nf = 0; nf < 4; ++nf) bfv[nf] = *(const v8s*)(bbase + nf * 1024);
        #pragma unroll
        for (int mf = 0; mf < 4; ++mf)
            #pragma unroll
            for (int nf = 0; nf < 4; ++nf)
                MFMA16(acc[mf][nf], af[mf], bfv[nf]);
    }
    asm volatile("s_nop 7\ns_nop 7" ::: );

    // epilogue: C/D layout col = lane&15 (pixel), row = (lane>>4)*4 + jj (o)
    int r = nt * 2 + wn;
    #pragma unroll
    for (int mf = 0; mf < 4; ++mf) {
        int o = wm * 64 + mf * 16 + ((lane >> 4) << 2);
        #pragma unroll
        for (int jj = 0; jj < 4; ++jj) {
            float* op = out + (((size_t)(b * OO + o + jj)) * HH + r) * WW;
            #pragma unroll
            for (int nf = 0; nf < 4; ++nf)
                op[nf * 16 + (lane & 15)] = acc[mf][nf][jj];
        }
    }
}

extern "C" void kernel_launch(void* const* d_in, const int* in_sizes, int n_in,
                              void* d_out, int out_size, void* d_ws, size_t ws_size,
                              hipStream_t stream) {
    const float* x       = (const float*)d_in[0];
    const float* w1      = (const float*)d_in[1];
    const float* b1      = (const float*)d_in[2];
    const float* w2      = (const float*)d_in[3];
    const float* b2      = (const float*)d_in[4];
    const float* kernels = (const float*)d_in[5];
    float* out = (float*)d_out;

    // ws layout: part[16*16*16*8] f32 | xbp[16*66*66*128] bf16 | wmixb[16*128*1152] bf16
    float* part = (float*)d_ws;
    unsigned short* xbp   = (unsigned short*)(part + 16 * 16 * 16 * 8);
    unsigned short* wmixb = xbp + (size_t)BB * XP * XP * CC;

    convert_pool_kernel<<<4096, 256, 0, stream>>>(x, xbp, part);
    mix_kernel<<<dim3(OO, BB), 256, 0, stream>>>(kernels, part, w1, b1, w2, b2, wmixb);
    conv_kernel<<<512, 256, 0, stream>>>(xbp, wmixb, out);
}